// Round 16
// baseline (856.820 us; speedup 1.0000x reference)
//
#include <hip/hip_runtime.h>
#include <hip/hip_bf16.h>
#include <cfloat>

#define B_TOTAL 131072
#define IN_DIM  768
#define NLEV    3
#define KCODE   256

typedef unsigned short u16;
typedef unsigned int   u32;
typedef __attribute__((ext_vector_type(8))) short bf16x8;
typedef __attribute__((ext_vector_type(4))) float f32x4;

#define GLOAD_LDS(g, l)                                                        \
    __builtin_amdgcn_global_load_lds(                                          \
        (const __attribute__((address_space(1))) u32*)(g),                     \
        (__attribute__((address_space(3))) u32*)(l), 16, 0, 0)

// LDS tile swizzle: row stride 64 B; 16-B slot q stored at q ^ SWZ(row).
#define SWZ(row) ((((row) >> 1) & 3u) << 4)

__device__ __forceinline__ u16 f2bf(float x) {
    union { __hip_bfloat16 h; u16 u; } c;
    c.h = __float2bfloat16(x);
    return c.u;
}
__device__ __forceinline__ float bf2f(u32 lo16) {
    union { u32 v; float f; } c;
    c.v = lo16 << 16;
    return c.f;
}
__device__ __forceinline__ u32 pack2(float a, float b) {
    return (u32)f2bf(a) | ((u32)f2bf(b) << 16);
}

__device__ __forceinline__ u32 xcd_swizzle(u32 orig, u32 nwg) {
    const u32 xcd = orig & 7u, q8 = nwg >> 3, r8 = nwg & 7u;
    return (xcd < r8 ? xcd * (q8 + 1) : r8 * (q8 + 1) + (xcd - r8) * q8)
           + (orig >> 3);
}

// ===========================================================================
// gemm_mfma: 256x128 tile, 8 waves (4Mx2N), BK=32, 3-buffer counted-vmcnt
// pipeline, one raw barrier per K-step, loads in flight across barriers.
// ===========================================================================
template<int K, int N, bool AF32, bool RELU, bool OUTF32>
__global__ __launch_bounds__(512)
void gemm_mfma(const void* __restrict__ A_, const u16* __restrict__ Wt,
               const float* __restrict__ bias, void* __restrict__ C_)
{
    constexpr int NK  = K / 32;
    constexpr int NCB = N / 128;
    __shared__ u16 As[3][8192];    // 256 x 32
    __shared__ u16 Bs[3][4096];    // 128 x 32

    const int tid  = threadIdx.x;
    const int lane = tid & 63;
    const int wid  = tid >> 6;
    const int wrow = wid >> 1;
    const int wcol = wid & 1;

    const u32 wg = xcd_swizzle(blockIdx.x, gridDim.x);
    const int col0 = (int)(wg % NCB) * 128;
    const int row0 = (int)(wg / NCB) * 256;

    const u16*   Ab = (const u16*)A_;
    const float* Af = (const float*)A_;

    f32x4 acc[4][4];
    #pragma unroll
    for (int i = 0; i < 4; ++i)
        #pragma unroll
        for (int j = 0; j < 4; ++j) acc[i][j] = (f32x4){0.f, 0.f, 0.f, 0.f};

    auto stage_B = [&](u16* dstbase, const u16* src) {
        const u32 o   = (u32)(tid * 16);
        const u32 row = o >> 6;
        const u32 cbs = (o & 63u) ^ SWZ(row);
        GLOAD_LDS((const char*)(src + (size_t)row * K) + cbs,
                  dstbase + wid * 512);
    };
    auto stage_A = [&](u16* dstbase, const u16* src) {
        #pragma unroll
        for (int i = 0; i < 2; ++i) {
            const u32 o   = (u32)(i * 8192 + tid * 16);
            const u32 row = o >> 6;
            const u32 cbs = (o & 63u) ^ SWZ(row);
            GLOAD_LDS((const char*)(src + (size_t)row * K) + cbs,
                      dstbase + (i * 4096 + wid * 512));
        }
    };
    auto stage_tile = [&](int buf, int kt) {
        stage_B(&Bs[buf][0], Wt + (size_t)col0 * K + kt * 32);
        stage_A(&As[buf][0], Ab + (size_t)row0 * K + kt * 32);
    };

    auto compute = [&](int buf) {
        const char* Ab8 = (const char*)&As[buf][0];
        const char* Bb8 = (const char*)&Bs[buf][0];
        const int kb = (lane >> 4) * 16;
        bf16x8 af[4], bf[4];
        #pragma unroll
        for (int mf = 0; mf < 4; ++mf) {
            const int r = wrow * 64 + mf * 16 + (lane & 15);
            af[mf] = *(const bf16x8*)(Ab8 + r * 64 + (kb ^ SWZ(r)));
        }
        #pragma unroll
        for (int nf = 0; nf < 4; ++nf) {
            const int r = wcol * 64 + nf * 16 + (lane & 15);
            bf[nf] = *(const bf16x8*)(Bb8 + r * 64 + (kb ^ SWZ(r)));
        }
        __builtin_amdgcn_s_setprio(1);
        #pragma unroll
        for (int mf = 0; mf < 4; ++mf)
            #pragma unroll
            for (int nf = 0; nf < 4; ++nf)
                acc[mf][nf] = __builtin_amdgcn_mfma_f32_16x16x32_bf16(
                    af[mf], bf[nf], acc[mf][nf], 0, 0, 0);
        __builtin_amdgcn_s_setprio(0);
    };

    if constexpr (AF32) {
        float4 fa[4];
        auto loadA = [&](int kt) {
            const int row = tid >> 1;
            const int ce0 = (tid & 1) * 16;
            const float* s = &Af[(size_t)(row0 + row) * K + kt * 32 + ce0];
            fa[0] = *(const float4*)(s + 0);
            fa[1] = *(const float4*)(s + 4);
            fa[2] = *(const float4*)(s + 8);
            fa[3] = *(const float4*)(s + 12);
        };
        auto writeA = [&](int buf) {
            const int row = tid >> 1;
            const u32 cb0 = (u32)((tid & 1) * 32);
            const u32 sw  = SWZ(row);
            char* lb = (char*)&As[buf][0] + row * 64;
            *(uint4*)(lb + ((cb0 + 0) ^ sw)) = make_uint4(
                pack2(fa[0].x, fa[0].y), pack2(fa[0].z, fa[0].w),
                pack2(fa[1].x, fa[1].y), pack2(fa[1].z, fa[1].w));
            *(uint4*)(lb + ((cb0 + 16) ^ sw)) = make_uint4(
                pack2(fa[2].x, fa[2].y), pack2(fa[2].z, fa[2].w),
                pack2(fa[3].x, fa[3].y), pack2(fa[3].z, fa[3].w));
        };

        loadA(0);
        stage_B(&Bs[0][0], Wt + (size_t)col0 * K);
        writeA(0);
        if (NK > 1) {
            loadA(1);
            stage_B(&Bs[1][0], Wt + (size_t)col0 * K + 32);
        }

        #pragma unroll 1
        for (int kt = 0; kt < NK; ++kt) {
            if (kt == NK - 1) asm volatile("s_waitcnt vmcnt(0) lgkmcnt(0)");
            else              asm volatile("s_waitcnt vmcnt(5) lgkmcnt(0)");
            __builtin_amdgcn_sched_barrier(0);
            __builtin_amdgcn_s_barrier();
            __builtin_amdgcn_sched_barrier(0);
            if (kt + 1 < NK) writeA((kt + 1) % 3);
            if (kt + 2 < NK) {
                loadA(kt + 2);
                stage_B(&Bs[(kt + 2) % 3][0],
                        Wt + (size_t)col0 * K + (kt + 2) * 32);
            }
            compute(kt % 3);
        }
    } else {
        stage_tile(0, 0);
        if (NK > 1) stage_tile(1, 1);
        int cb_ = 0, sb_ = 2;
        #pragma unroll 1
        for (int kt = 0; kt < NK; ++kt) {
            if (kt == NK - 1) asm volatile("s_waitcnt vmcnt(0)");
            else              asm volatile("s_waitcnt vmcnt(3)");
            __builtin_amdgcn_sched_barrier(0);
            __builtin_amdgcn_s_barrier();
            __builtin_amdgcn_sched_barrier(0);
            if (kt + 2 < NK) stage_tile(sb_, kt + 2);
            compute(cb_);
            cb_ = (cb_ == 2) ? 0 : cb_ + 1;
            sb_ = (sb_ == 2) ? 0 : sb_ + 1;
        }
    }

    #pragma unroll
    for (int nf = 0; nf < 4; ++nf) {
        const int col = col0 + wcol * 64 + nf * 16 + (lane & 15);
        const float bv = bias[col];
        #pragma unroll
        for (int mf = 0; mf < 4; ++mf) {
            const int rbase = row0 + wrow * 64 + mf * 16 + (lane >> 4) * 4;
            #pragma unroll
            for (int r = 0; r < 4; ++r) {
                float o = acc[mf][nf][r] + bv;
                if (RELU) o = fmaxf(o, 0.f);
                if constexpr (OUTF32)
                    ((float*)C_)[(size_t)(rbase + r) * N + col] = o;
                else
                    ((u16*)C_)[(size_t)(rbase + r) * N + col] = f2bf(o);
            }
        }
    }
}

// ===========================================================================
// prep: all 7 weight convert+transposes + hist zero in ONE kernel.
// ===========================================================================
__global__ __launch_bounds__(256)
void prep(const float* __restrict__ eW0, const float* __restrict__ eW1,
          const float* __restrict__ eW2, const float* __restrict__ dW0,
          const float* __restrict__ dW1, const float* __restrict__ dW2,
          const float* __restrict__ dW3,
          u16* __restrict__ tE0, u16* __restrict__ tE1, u16* __restrict__ tE2,
          u16* __restrict__ tD0, u16* __restrict__ tD1, u16* __restrict__ tD2,
          u16* __restrict__ tD3, u32* __restrict__ ghist)
{
    const int i = blockIdx.x * 256 + threadIdx.x;
    if (i < 393216) {
        const int k = i >> 9, n = i & 511;
        tE0[(size_t)n * 768 + k] = f2bf(eW0[i]);
    } else if (i < 524288) {
        const int j = i - 393216, k = j >> 8, n = j & 255;
        tE1[(size_t)n * 512 + k] = f2bf(eW1[j]);
    } else if (i < 557056) {
        const int j = i - 524288, k = j >> 7, n = j & 127;
        tE2[(size_t)n * 256 + k] = f2bf(eW2[j]);
    } else if (i < 561152) {
        const int j = i - 557056, k = j >> 7, n = j & 127;
        tD0[(size_t)n * 32 + k] = f2bf(dW0[j]);
    } else if (i < 593920) {
        const int j = i - 561152, k = j >> 8, n = j & 255;
        tD1[(size_t)n * 128 + k] = f2bf(dW1[j]);
    } else if (i < 724992) {
        const int j = i - 593920, k = j >> 9, n = j & 511;
        tD2[(size_t)n * 256 + k] = f2bf(dW2[j]);
    } else if (i < 1118208) {
        const int j = i - 724992, k = j / 768, n = j - k * 768;
        tD3[(size_t)n * 512 + k] = f2bf(dW3[j]);
    } else if (i < 1118976) {
        ghist[i - 1118208] = 0;
    }
}

// ===========================================================================
// VQ+D0 fused kernel: 512 threads, one row per thread (512 rows/block).
// Phase 1: z = h3 @ eW3 + eb3 (W3 from LDS broadcast).
// Phase 2: 3-level RVQ scan (codebook in LDS, broadcast), writes r/e/q f32.
// Phase 3: d1 = relu((z0 - r_final) @ dW0 + db0) -> bf16 ws (D0 absorbed;
//          se stays f32 in registers -> better numerics, no round-trip).
// ===========================================================================
__global__ __launch_bounds__(512)
void vq_kernel(const u16* __restrict__ h3, const float* __restrict__ eW3,
               const float* __restrict__ eb3, const float* __restrict__ cb,
               const float* __restrict__ dW0, const float* __restrict__ db0,
               float* __restrict__ r_out, float* __restrict__ e_out,
               float* __restrict__ q_out, u16* __restrict__ d1_out,
               u32* __restrict__ ghist, size_t grow_base)
{
    __shared__ float Wb[128 * 32];     // 16 KiB: eW3 in phase 1, dW0 in phase 3
    __shared__ float ebv[32];
    __shared__ float dbv[128];
    __shared__ float clds[256 * 36];   // 36 KiB
    __shared__ float cc2[256];
    __shared__ u32   lh[NLEV * KCODE];

    const int tid = threadIdx.x;
    const size_t lrow = (size_t)blockIdx.x * 512 + tid;
    const size_t grow = grow_base + lrow;

    for (int i = tid; i < 128 * 32; i += 512) Wb[i] = eW3[i];
    if (tid < 32)  ebv[tid] = eb3[tid];
    if (tid < 128) dbv[tid] = db0[tid];
    for (int i = tid; i < NLEV * KCODE; i += 512) lh[i] = 0;
    __syncthreads();

    // z = h3[row] @ W3 + b  (h3 bf16, accum f32)
    float r[32];
    #pragma unroll
    for (int j = 0; j < 32; ++j) r[j] = ebv[j];
    {
        const u32* hrow = (const u32*)h3 + lrow * 64;
        #pragma unroll 2
        for (int k2 = 0; k2 < 64; ++k2) {
            const u32 v = hrow[k2];
            const float x0 = bf2f(v & 0xffffu), x1 = bf2f(v >> 16);
            const float* w0 = &Wb[(2 * k2) * 32];
            const float* w1 = &Wb[(2 * k2 + 1) * 32];
            #pragma unroll
            for (int j4 = 0; j4 < 8; ++j4) {
                const float4 a = *(const float4*)&w0[4 * j4];
                const float4 b = *(const float4*)&w1[4 * j4];
                r[4*j4+0] = fmaf(x1, b.x, fmaf(x0, a.x, r[4*j4+0]));
                r[4*j4+1] = fmaf(x1, b.y, fmaf(x0, a.y, r[4*j4+1]));
                r[4*j4+2] = fmaf(x1, b.z, fmaf(x0, a.z, r[4*j4+2]));
                r[4*j4+3] = fmaf(x1, b.w, fmaf(x0, a.w, r[4*j4+3]));
            }
        }
    }

    float z0[32];
    #pragma unroll
    for (int j = 0; j < 32; ++j) z0[j] = r[j];

    #pragma unroll 1
    for (int l = 0; l < NLEV; ++l) {
        __syncthreads();
        if (tid < KCODE) {   // stage codebook level l: thread t owns code t
            const float* cl = cb + ((size_t)l * KCODE + tid) * 32;
            float s = 0.f;
            #pragma unroll
            for (int m = 0; m < 8; ++m) {
                const float4 v = *(const float4*)&cl[4 * m];
                *(float4*)&clds[tid * 36 + 4 * m] = v;
                s = fmaf(v.x, v.x, s); s = fmaf(v.y, v.y, s);
                s = fmaf(v.z, v.z, s); s = fmaf(v.w, v.w, s);
            }
            cc2[tid] = -0.5f * s;
        }
        __syncthreads();

        float best = -FLT_MAX;
        int   bidx = 0;
        #pragma unroll 1
        for (int k = 0; k < KCODE; ++k) {
            const float* ck = &clds[k * 36];
            float d0 = 0.f, d1 = 0.f, d2 = 0.f, d3 = 0.f;
            #pragma unroll
            for (int m = 0; m < 8; m += 4) {
                const float4 v0 = *(const float4*)&ck[4 * (m + 0)];
                const float4 v1 = *(const float4*)&ck[4 * (m + 1)];
                const float4 v2 = *(const float4*)&ck[4 * (m + 2)];
                const float4 v3 = *(const float4*)&ck[4 * (m + 3)];
                d0 = fmaf(r[4*m+0],  v0.x, d0); d0 = fmaf(r[4*m+1],  v0.y, d0);
                d0 = fmaf(r[4*m+2],  v0.z, d0); d0 = fmaf(r[4*m+3],  v0.w, d0);
                d1 = fmaf(r[4*m+4],  v1.x, d1); d1 = fmaf(r[4*m+5],  v1.y, d1);
                d1 = fmaf(r[4*m+6],  v1.z, d1); d1 = fmaf(r[4*m+7],  v1.w, d1);
                d2 = fmaf(r[4*m+8],  v2.x, d2); d2 = fmaf(r[4*m+9],  v2.y, d2);
                d2 = fmaf(r[4*m+10], v2.z, d2); d2 = fmaf(r[4*m+11], v2.w, d2);
                d3 = fmaf(r[4*m+12], v3.x, d3); d3 = fmaf(r[4*m+13], v3.y, d3);
                d3 = fmaf(r[4*m+14], v3.z, d3); d3 = fmaf(r[4*m+15], v3.w, d3);
            }
            const float s = ((d0 + d1) + (d2 + d3)) + cc2[k];
            if (s > best) { best = s; bidx = k; }
        }

        const size_t base = (grow * NLEV + l) * 32;
        const float* ce = &clds[bidx * 36];
        #pragma unroll
        for (int m = 0; m < 8; ++m) {
            const float4 ev = *(const float4*)&ce[4 * m];
            *(float4*)&r_out[base + 4 * m] =
                make_float4(r[4*m+0], r[4*m+1], r[4*m+2], r[4*m+3]);
            *(float4*)&e_out[base + 4 * m] = ev;
            r[4*m+0] -= ev.x; r[4*m+1] -= ev.y;
            r[4*m+2] -= ev.z; r[4*m+3] -= ev.w;
        }
        q_out[grow * NLEV + l] = (float)bidx;
        atomicAdd(&lh[l * KCODE + bidx], 1u);
    }

    // ---- Phase 3: D0 fused. se = z0 - r_final (f32, in regs). ----
    __syncthreads();                         // scan reads of Wb long done; clds done
    for (int i = tid; i < 128 * 32; i += 512) Wb[i] = dW0[i];
    __syncthreads();

    float se[32];
    #pragma unroll
    for (int j = 0; j < 32; ++j) se[j] = z0[j] - r[j];

    u16* drow = d1_out + lrow * 128;
    #pragma unroll 2
    for (int q4 = 0; q4 < 32; ++q4) {
        float4 a = *(const float4*)&dbv[4 * q4];
        #pragma unroll
        for (int k = 0; k < 32; ++k) {
            const float4 w = *(const float4*)&Wb[k * 128 + 4 * q4];
            a.x = fmaf(se[k], w.x, a.x);
            a.y = fmaf(se[k], w.y, a.y);
            a.z = fmaf(se[k], w.z, a.z);
            a.w = fmaf(se[k], w.w, a.w);
        }
        a.x = fmaxf(a.x, 0.f); a.y = fmaxf(a.y, 0.f);
        a.z = fmaxf(a.z, 0.f); a.w = fmaxf(a.w, 0.f);
        *(uint2*)&drow[4 * q4] = make_uint2(pack2(a.x, a.y), pack2(a.z, a.w));
    }

    __syncthreads();
    for (int i = tid; i < NLEV * KCODE; i += 512)
        if (lh[i]) atomicAdd(&ghist[i], lh[i]);
}

__global__ void counts_fin(const u32* __restrict__ g, float* __restrict__ o) {
    if (threadIdx.x < NLEV * KCODE) o[threadIdx.x] = (float)g[threadIdx.x];
}

__global__ __launch_bounds__(256)
void counts_k(const float* __restrict__ q, float* __restrict__ cnt)
{
    const int l = blockIdx.x >> 8;
    const int k = blockIdx.x & 255;
    const float pat = (float)k;
    int c = 0;
    for (int i = threadIdx.x; i < B_TOTAL; i += 256)
        c += (q[(size_t)i * NLEV + l] == pat) ? 1 : 0;
    __shared__ int red[256];
    red[threadIdx.x] = c;
    __syncthreads();
    for (int s = 128; s > 0; s >>= 1) {
        if (threadIdx.x < s) red[threadIdx.x] += red[threadIdx.x + s];
        __syncthreads();
    }
    if (threadIdx.x == 0)
        cnt[blockIdx.x] = (float)red[0];
}

// ===========================================================================
// Fallback path (R6-proven, f32 VALU, zero workspace).
// ===========================================================================
template<int K, int N, bool RELU, bool AGLOBAL>
static __device__ __forceinline__
void layer16(const float* __restrict__ A, size_t grow0,
             const float* __restrict__ W, const float* __restrict__ bias,
             float* __restrict__ C)
{
    constexpr int QPT = N / 128;
    const int tr = threadIdx.x >> 5;
    const int tc = threadIdx.x & 31;
    float acc[2][QPT * 4];
    #pragma unroll
    for (int i = 0; i < 2; ++i)
        #pragma unroll
        for (int j = 0; j < QPT * 4; ++j) acc[i][j] = 0.f;
    #pragma unroll 2
    for (int k0 = 0; k0 < K; k0 += 4) {
        float4 av[2];
        #pragma unroll
        for (int i = 0; i < 2; ++i) {
            if (AGLOBAL)
                av[i] = *(const float4*)&A[(grow0 + tr * 2 + i) * (size_t)K + k0];
            else
                av[i] = *(const float4*)&A[(tr * 2 + i) * K + k0];
        }
        #pragma unroll
        for (int kk = 0; kk < 4; ++kk) {
            #pragma unroll
            for (int q = 0; q < QPT; ++q) {
                const float4 w4 = *(const float4*)&W[(size_t)(k0 + kk) * N + 4 * (tc + 32 * q)];
                #pragma unroll
                for (int i = 0; i < 2; ++i) {
                    const float a = ((const float*)&av[i])[kk];
                    acc[i][4*q+0] = fmaf(a, w4.x, acc[i][4*q+0]);
                    acc[i][4*q+1] = fmaf(a, w4.y, acc[i][4*q+1]);
                    acc[i][4*q+2] = fmaf(a, w4.z, acc[i][4*q+2]);
                    acc[i][4*q+3] = fmaf(a, w4.w, acc[i][4*q+3]);
                }
            }
        }
    }
    #pragma unroll
    for (int q = 0; q < QPT; ++q) {
        const float4 b4 = *(const float4*)&bias[4 * (tc + 32 * q)];
        #pragma unroll
        for (int i = 0; i < 2; ++i) {
            float4 o;
            o.x = acc[i][4*q+0] + b4.x; o.y = acc[i][4*q+1] + b4.y;
            o.z = acc[i][4*q+2] + b4.z; o.w = acc[i][4*q+3] + b4.w;
            if (RELU) {
                o.x = fmaxf(o.x, 0.f); o.y = fmaxf(o.y, 0.f);
                o.z = fmaxf(o.z, 0.f); o.w = fmaxf(o.w, 0.f);
            }
            *(float4*)&C[(tr * 2 + i) * N + 4 * (tc + 32 * q)] = o;
        }
    }
}

static __device__ __forceinline__
void layer_final16(const float* __restrict__ A, const float* __restrict__ W,
                   const float* __restrict__ bias, float* __restrict__ Cg, size_t grow0)
{
    constexpr int QPT = 6;
    const int tr = threadIdx.x >> 5;
    const int tc = threadIdx.x & 31;
    float acc[2][QPT * 4];
    #pragma unroll
    for (int i = 0; i < 2; ++i)
        #pragma unroll
        for (int j = 0; j < QPT * 4; ++j) acc[i][j] = 0.f;
    #pragma unroll 2
    for (int k0 = 0; k0 < 512; k0 += 4) {
        float4 av[2];
        #pragma unroll
        for (int i = 0; i < 2; ++i)
            av[i] = *(const float4*)&A[(tr * 2 + i) * 512 + k0];
        #pragma unroll
        for (int kk = 0; kk < 4; ++kk) {
            #pragma unroll
            for (int q = 0; q < QPT; ++q) {
                const float4 w4 = *(const float4*)&W[(size_t)(k0 + kk) * 768 + 4 * (tc + 32 * q)];
                #pragma unroll
                for (int i = 0; i < 2; ++i) {
                    const float a = ((const float*)&av[i])[kk];
                    acc[i][4*q+0] = fmaf(a, w4.x, acc[i][4*q+0]);
                    acc[i][4*q+1] = fmaf(a, w4.y, acc[i][4*q+1]);
                    acc[i][4*q+2] = fmaf(a, w4.z, acc[i][4*q+2]);
                    acc[i][4*q+3] = fmaf(a, w4.w, acc[i][4*q+3]);
                }
            }
        }
    }
    #pragma unroll
    for (int q = 0; q < QPT; ++q) {
        const float4 b4 = *(const float4*)&bias[4 * (tc + 32 * q)];
        #pragma unroll
        for (int i = 0; i < 2; ++i) {
            float4 s;
            s.x = acc[i][4*q+0] + b4.x; s.y = acc[i][4*q+1] + b4.y;
            s.z = acc[i][4*q+2] + b4.z; s.w = acc[i][4*q+3] + b4.w;
            *(float4*)&Cg[(grow0 + tr * 2 + i) * (size_t)768 + 4 * (tc + 32 * q)] = s;
        }
    }
}

static __device__ __forceinline__
void layer_narrow16(const float* __restrict__ A, const float* __restrict__ W,
                    const float* __restrict__ bias, float* __restrict__ Z)
{
    const int row = threadIdx.x >> 4;
    const int g   = threadIdx.x & 15;
    float a0 = 0.f, a1 = 0.f;
    #pragma unroll 4
    for (int k0 = 0; k0 < 128; k0 += 4) {
        const float4 av = *(const float4*)&A[row * 128 + k0];
        #pragma unroll
        for (int kk = 0; kk < 4; ++kk) {
            const float2 w2 = *(const float2*)&W[(k0 + kk) * 32 + 2 * g];
            const float a = ((const float*)&av)[kk];
            a0 = fmaf(a, w2.x, a0);
            a1 = fmaf(a, w2.y, a1);
        }
    }
    Z[row * 36 + 2 * g + 0] = a0 + bias[2 * g + 0];
    Z[row * 36 + 2 * g + 1] = a1 + bias[2 * g + 1];
}

__global__ __launch_bounds__(256)
void enc_vq_kernel(const float* __restrict__ x,
                   const float* __restrict__ eW0, const float* __restrict__ eb0,
                   const float* __restrict__ eW1, const float* __restrict__ eb1,
                   const float* __restrict__ eW2, const float* __restrict__ eb2,
                   const float* __restrict__ eW3, const float* __restrict__ eb3,
                   const float* __restrict__ cb,
                   float* __restrict__ r_out, float* __restrict__ e_out,
                   float* __restrict__ q_out)
{
    __shared__ __align__(16) char smem[59648];
    float* h1   = (float*)(smem);
    float* h2   = (float*)(smem + 32768);
    float* h3   = (float*)(smem + 49152);
    float* z    = (float*)(smem + 57344);
    float* clds = (float*)(smem);
    float* cc   = (float*)(smem + 36864);

    const size_t grow0 = (size_t)blockIdx.x * 16;
    layer16<768, 512, true, true >(x,  grow0, eW0, eb0, h1);
    __syncthreads();
    layer16<512, 256, true, false>(h1, 0,     eW1, eb1, h2);
    __syncthreads();
    layer16<256, 128, true, false>(h2, 0,     eW2, eb2, h3);
    __syncthreads();
    layer_narrow16(h3, eW3, eb3, z);

    const int row = threadIdx.x >> 4;
    const int g   = threadIdx.x & 15;
    const size_t grow = grow0 + row;

    #pragma unroll 1
    for (int l = 0; l < NLEV; ++l) {
        __syncthreads();
        {
            const float* cl = cb + (size_t)l * KCODE * 32;
            const int t = threadIdx.x;
            float s = 0.f;
            #pragma unroll
            for (int m = 0; m < 8; ++m) {
                const float4 v = *(const float4*)&cl[t * 32 + 4 * m];
                *(float4*)&clds[t * 36 + 4 * m] = v;
                s = fmaf(v.x, v.x, s); s = fmaf(v.y, v.y, s);
                s = fmaf(v.z, v.z, s); s = fmaf(v.w, v.w, s);
            }
            cc[t] = s;
        }
        __syncthreads();

        float r[32];
        #pragma unroll
        for (int m = 0; m < 8; ++m) {
            const float4 v = *(const float4*)&z[row * 36 + 4 * m];
            r[4*m+0] = v.x; r[4*m+1] = v.y; r[4*m+2] = v.z; r[4*m+3] = v.w;
        }
        float rr = 0.f;
        #pragma unroll
        for (int j = 0; j < 32; ++j) rr = fmaf(r[j], r[j], rr);

        float best = FLT_MAX;
        int   bidx = 0x7fffffff;
        #pragma unroll 1
        for (int t = 0; t < 16; ++t) {
            const int k = g + 16 * t;
            const float* ck = &clds[k * 36];
            float d0 = 0.f, d1 = 0.f, d2 = 0.f, d3 = 0.f;
            #pragma unroll
            for (int m = 0; m < 8; m += 4) {
                const float4 v0 = *(const float4*)&ck[4 * (m + 0)];
                const float4 v1 = *(const float4*)&ck[4 * (m + 1)];
                const float4 v2 = *(const float4*)&ck[4 * (m + 2)];
                const float4 v3 = *(const float4*)&ck[4 * (m + 3)];
                d0 = fmaf(r[4*m+0],  v0.x, d0); d0 = fmaf(r[4*m+1],  v0.y, d0);
                d0 = fmaf(r[4*m+2],  v0.z, d0); d0 = fmaf(r[4*m+3],  v0.w, d0);
                d1 = fmaf(r[4*m+4],  v1.x, d1); d1 = fmaf(r[4*m+5],  v1.y, d1);
                d1 = fmaf(r[4*m+6],  v1.z, d1); d1 = fmaf(r[4*m+7],  v1.w, d1);
                d2 = fmaf(r[4*m+8],  v2.x, d2); d2 = fmaf(r[4*m+9],  v2.y, d2);
                d2 = fmaf(r[4*m+10], v2.z, d2); d2 = fmaf(r[4*m+11], v2.w, d2);
                d3 = fmaf(r[4*m+12], v3.x, d3); d3 = fmaf(r[4*m+13], v3.y, d3);
                d3 = fmaf(r[4*m+14], v3.z, d3); d3 = fmaf(r[4*m+15], v3.w, d3);
            }
            const float dot = (d0 + d1) + (d2 + d3);
            const float d = (rr - 2.f * dot) + cc[k];
            if (d < best || (d == best && k < bidx)) { best = d; bidx = k; }
        }
        #pragma unroll
        for (int off = 1; off < 16; off <<= 1) {
            const float ob = __shfl_xor(best, off);
            const int   oi = __shfl_xor(bidx, off);
            if (ob < best || (ob == best && oi < bidx)) { best = ob; bidx = oi; }
        }

        const float evx = clds[bidx * 36 + 2 * g + 0];
        const float evy = clds[bidx * 36 + 2 * g + 1];
        *(float2*)&r_out[(grow * NLEV + l) * 32 + 2 * g] = make_float2(r[2*g], r[2*g+1]);
        *(float2*)&e_out[(grow * NLEV + l) * 32 + 2 * g] = make_float2(evx, evy);
        if (g == 0) q_out[grow * NLEV + l] = (float)bidx;
        z[row * 36 + 2 * g + 0] = r[2 * g + 0] - evx;
        z[row * 36 + 2 * g + 1] = r[2 * g + 1] - evy;
    }
}

__global__ __launch_bounds__(256)
void dec_kernel(const float* __restrict__ e_in,
                const float* __restrict__ dW0, const float* __restrict__ db0,
                const float* __restrict__ dW1, const float* __restrict__ db1,
                const float* __restrict__ dW2, const float* __restrict__ db2,
                const float* __restrict__ dW3, const float* __restrict__ db3,
                float* __restrict__ dec_out)
{
    __shared__ __align__(16) char smem[59392];
    float* h3 = (float*)(smem);
    float* h2 = (float*)(smem + 32768);
    float* h1 = (float*)(smem + 49152);
    float* se = (float*)(smem + 57344);

    const size_t grow0 = (size_t)blockIdx.x * 16;
    const int row = threadIdx.x >> 4;
    const int g   = threadIdx.x & 15;
    {
        const size_t base = ((grow0 + row) * NLEV) * 32 + 2 * g;
        float s0 = 0.f, s1 = 0.f;
        #pragma unroll
        for (int l = 0; l < NLEV; ++l) {
            const float2 v = *(const float2*)&e_in[base + l * 32];
            s0 += v.x; s1 += v.y;
        }
        se[row * 32 + 2 * g + 0] = s0;
        se[row * 32 + 2 * g + 1] = s1;
    }
    __syncthreads();
    layer16<32,  128, true, false>(se, 0, dW0, db0, h1);
    __syncthreads();
    layer16<128, 256, true, false>(h1, 0, dW1, db1, h2);
    __syncthreads();
    layer16<256, 512, true, false>(h2, 0, dW2, db2, h3);
    __syncthreads();
    layer_final16(h3, dW3, db3, dec_out, grow0);
}

// ===========================================================================
extern "C" void kernel_launch(void* const* d_in, const int* in_sizes, int n_in,
                              void* d_out, int out_size, void* d_ws, size_t ws_size,
                              hipStream_t stream)
{
    (void)in_sizes; (void)n_in; (void)out_size;
    const float* x  = (const float*)d_in[0];
    const float* cb = (const float*)d_in[17];
    const float *eW[4], *eb[4], *dW[4], *db[4];
    for (int i = 0; i < 4; ++i) {
        eW[i] = (const float*)d_in[1 + 4 * i];
        eb[i] = (const float*)d_in[2 + 4 * i];
        dW[i] = (const float*)d_in[3 + 4 * i];
        db[i] = (const float*)d_in[4 + 4 * i];
    }

    float* out = (float*)d_out;
    const size_t OFF_R = (size_t)B_TOTAL * IN_DIM;
    const size_t OFF_E = OFF_R + (size_t)B_TOTAL * NLEV * 32;
    const size_t OFF_C = OFF_E + (size_t)B_TOTAL * NLEV * 32;
    const size_t OFF_Q = OFF_C + (size_t)NLEV * KCODE;

    const size_t WTB = 2236416;                 // weights bf16, bytes
    size_t R = 0;
    for (size_t cand = 131072; cand >= 2048; cand >>= 1)
        if (WTB + cand * 3648 + 4096 <= ws_size) { R = cand; break; }

    if (R && d_ws) {
        u16* Wp   = (u16*)d_ws;
        u16* WtE0 = Wp;
        u16* WtE1 = WtE0 + 393216;
        u16* WtE2 = WtE1 + 131072;
        u16* WtD0 = WtE2 + 32768;
        u16* WtD1 = WtD0 + 4096;
        u16* WtD2 = WtD1 + 32768;
        u16* WtD3 = WtD2 + 131072;
        u16* h1   = WtD3 + 393216;
        u16* h2   = h1 + R * 512;
        u16* h3   = h2 + R * 256;
        u16* d1   = h3 + R * 128;
        u16* d2   = d1 + R * 128;
        u16* d3   = d2 + R * 256;
        u32* ghist = (u32*)(d3 + R * 512);

        prep<<<dim3(4371), 256, 0, stream>>>(
            eW[0], eW[1], eW[2], dW[0], dW[1], dW[2], dW[3],
            WtE0, WtE1, WtE2, WtD0, WtD1, WtD2, WtD3, ghist);

        const int nch = B_TOTAL / (int)R;
        const int MB2 = (int)R / 256;          // 256-row blocks
        for (int c = 0; c < nch; ++c) {
            const size_t rb = (size_t)c * R;
            gemm_mfma<768, 512, true,  true,  false><<<dim3(4 * MB2), 512, 0, stream>>>(
                x + rb * 768, WtE0, eb[0], h1);
            gemm_mfma<512, 256, false, true,  false><<<dim3(2 * MB2), 512, 0, stream>>>(
                h1, WtE1, eb[1], h2);
            gemm_mfma<256, 128, false, true,  false><<<dim3(1 * MB2), 512, 0, stream>>>(
                h2, WtE2, eb[2], h3);
            vq_kernel<<<dim3((int)R / 512), 512, 0, stream>>>(
                h3, eW[3], eb[3], cb, dW[0], db[0],
                out + OFF_R, out + OFF_E, out + OFF_Q, d1, ghist, rb);
            gemm_mfma<128, 256, false, true,  false><<<dim3(2 * MB2), 512, 0, stream>>>(
                d1, WtD1, db[1], d2);
            gemm_mfma<256, 512, false, true,  false><<<dim3(4 * MB2), 512, 0, stream>>>(
                d2, WtD2, db[2], d3);
            gemm_mfma<512, 768, false, false, true ><<<dim3(6 * MB2), 512, 0, stream>>>(
                d3, WtD3, db[3], out + rb * 768);
        }
        counts_fin<<<1, 768, 0, stream>>>(ghist, out + OFF_C);
    } else {
        enc_vq_kernel<<<dim3(B_TOTAL / 16), 256, 0, stream>>>(
            x, eW[0], eb[0], eW[1], eb[1], eW[2], eb[2], eW[3], eb[3], cb,
            out + OFF_R, out + OFF_E, out + OFF_Q);
        counts_k<<<dim3(NLEV * KCODE), 256, 0, stream>>>(out + OFF_Q, out + OFF_C);
        dec_kernel<<<dim3(B_TOTAL / 16), 256, 0, stream>>>(
            out + OFF_E, dW[0], db[0], dW[1], db[1], dW[2], db[2], dW[3], db[3], out);
    }
}

// Round 17
// 836.799 us; speedup vs baseline: 1.0239x; 1.0239x over previous
//
#include <hip/hip_runtime.h>
#include <hip/hip_bf16.h>
#include <cfloat>

#define B_TOTAL 131072
#define IN_DIM  768
#define NLEV    3
#define KCODE   256

typedef unsigned short u16;
typedef unsigned int   u32;
typedef __attribute__((ext_vector_type(8))) short bf16x8;
typedef __attribute__((ext_vector_type(4))) float f32x4;

#define GLOAD_LDS(g, l)                                                        \
    __builtin_amdgcn_global_load_lds(                                          \
        (const __attribute__((address_space(1))) u32*)(g),                     \
        (__attribute__((address_space(3))) u32*)(l), 16, 0, 0)

// LDS tile swizzle: row stride 64 B; 16-B slot q stored at q ^ SWZ(row).
#define SWZ(row) ((((row) >> 1) & 3u) << 4)

__device__ __forceinline__ u16 f2bf(float x) {
    union { __hip_bfloat16 h; u16 u; } c;
    c.h = __float2bfloat16(x);
    return c.u;
}
__device__ __forceinline__ float bf2f(u32 lo16) {
    union { u32 v; float f; } c;
    c.v = lo16 << 16;
    return c.f;
}
__device__ __forceinline__ u32 pack2(float a, float b) {
    return (u32)f2bf(a) | ((u32)f2bf(b) << 16);
}

__device__ __forceinline__ u32 xcd_swizzle(u32 orig, u32 nwg) {
    const u32 xcd = orig & 7u, q8 = nwg >> 3, r8 = nwg & 7u;
    return (xcd < r8 ? xcd * (q8 + 1) : r8 * (q8 + 1) + (xcd - r8) * q8)
           + (orig >> 3);
}

// ===========================================================================
// gemm_mfma: 256x128 tile, 8 waves (4Mx2N), BK=32, 3-buffer counted-vmcnt
// pipeline, one raw barrier per K-step, loads in flight across barriers.
// ===========================================================================
template<int K, int N, bool AF32, bool RELU, bool OUTF32>
__global__ __launch_bounds__(512)
void gemm_mfma(const void* __restrict__ A_, const u16* __restrict__ Wt,
               const float* __restrict__ bias, void* __restrict__ C_)
{
    constexpr int NK  = K / 32;
    constexpr int NCB = N / 128;
    __shared__ u16 As[3][8192];    // 256 x 32
    __shared__ u16 Bs[3][4096];    // 128 x 32

    const int tid  = threadIdx.x;
    const int lane = tid & 63;
    const int wid  = tid >> 6;
    const int wrow = wid >> 1;
    const int wcol = wid & 1;

    const u32 wg = xcd_swizzle(blockIdx.x, gridDim.x);
    const int col0 = (int)(wg % NCB) * 128;
    const int row0 = (int)(wg / NCB) * 256;

    const u16*   Ab = (const u16*)A_;
    const float* Af = (const float*)A_;

    f32x4 acc[4][4];
    #pragma unroll
    for (int i = 0; i < 4; ++i)
        #pragma unroll
        for (int j = 0; j < 4; ++j) acc[i][j] = (f32x4){0.f, 0.f, 0.f, 0.f};

    auto stage_B = [&](u16* dstbase, const u16* src) {
        const u32 o   = (u32)(tid * 16);
        const u32 row = o >> 6;
        const u32 cbs = (o & 63u) ^ SWZ(row);
        GLOAD_LDS((const char*)(src + (size_t)row * K) + cbs,
                  dstbase + wid * 512);
    };
    auto stage_A = [&](u16* dstbase, const u16* src) {
        #pragma unroll
        for (int i = 0; i < 2; ++i) {
            const u32 o   = (u32)(i * 8192 + tid * 16);
            const u32 row = o >> 6;
            const u32 cbs = (o & 63u) ^ SWZ(row);
            GLOAD_LDS((const char*)(src + (size_t)row * K) + cbs,
                      dstbase + (i * 4096 + wid * 512));
        }
    };
    auto stage_tile = [&](int buf, int kt) {
        stage_B(&Bs[buf][0], Wt + (size_t)col0 * K + kt * 32);
        stage_A(&As[buf][0], Ab + (size_t)row0 * K + kt * 32);
    };

    auto compute = [&](int buf) {
        const char* Ab8 = (const char*)&As[buf][0];
        const char* Bb8 = (const char*)&Bs[buf][0];
        const int kb = (lane >> 4) * 16;
        bf16x8 af[4], bf[4];
        #pragma unroll
        for (int mf = 0; mf < 4; ++mf) {
            const int r = wrow * 64 + mf * 16 + (lane & 15);
            af[mf] = *(const bf16x8*)(Ab8 + r * 64 + (kb ^ SWZ(r)));
        }
        #pragma unroll
        for (int nf = 0; nf < 4; ++nf) {
            const int r = wcol * 64 + nf * 16 + (lane & 15);
            bf[nf] = *(const bf16x8*)(Bb8 + r * 64 + (kb ^ SWZ(r)));
        }
        __builtin_amdgcn_s_setprio(1);
        #pragma unroll
        for (int mf = 0; mf < 4; ++mf)
            #pragma unroll
            for (int nf = 0; nf < 4; ++nf)
                acc[mf][nf] = __builtin_amdgcn_mfma_f32_16x16x32_bf16(
                    af[mf], bf[nf], acc[mf][nf], 0, 0, 0);
        __builtin_amdgcn_s_setprio(0);
    };

    if constexpr (AF32) {
        float4 fa[4];
        auto loadA = [&](int kt) {
            const int row = tid >> 1;
            const int ce0 = (tid & 1) * 16;
            const float* s = &Af[(size_t)(row0 + row) * K + kt * 32 + ce0];
            fa[0] = *(const float4*)(s + 0);
            fa[1] = *(const float4*)(s + 4);
            fa[2] = *(const float4*)(s + 8);
            fa[3] = *(const float4*)(s + 12);
        };
        auto writeA = [&](int buf) {
            const int row = tid >> 1;
            const u32 cb0 = (u32)((tid & 1) * 32);
            const u32 sw  = SWZ(row);
            char* lb = (char*)&As[buf][0] + row * 64;
            *(uint4*)(lb + ((cb0 + 0) ^ sw)) = make_uint4(
                pack2(fa[0].x, fa[0].y), pack2(fa[0].z, fa[0].w),
                pack2(fa[1].x, fa[1].y), pack2(fa[1].z, fa[1].w));
            *(uint4*)(lb + ((cb0 + 16) ^ sw)) = make_uint4(
                pack2(fa[2].x, fa[2].y), pack2(fa[2].z, fa[2].w),
                pack2(fa[3].x, fa[3].y), pack2(fa[3].z, fa[3].w));
        };

        loadA(0);
        stage_B(&Bs[0][0], Wt + (size_t)col0 * K);
        writeA(0);
        if (NK > 1) {
            loadA(1);
            stage_B(&Bs[1][0], Wt + (size_t)col0 * K + 32);
        }

        #pragma unroll 1
        for (int kt = 0; kt < NK; ++kt) {
            if (kt == NK - 1) asm volatile("s_waitcnt vmcnt(0) lgkmcnt(0)");
            else              asm volatile("s_waitcnt vmcnt(5) lgkmcnt(0)");
            __builtin_amdgcn_sched_barrier(0);
            __builtin_amdgcn_s_barrier();
            __builtin_amdgcn_sched_barrier(0);
            if (kt + 1 < NK) writeA((kt + 1) % 3);
            if (kt + 2 < NK) {
                loadA(kt + 2);
                stage_B(&Bs[(kt + 2) % 3][0],
                        Wt + (size_t)col0 * K + (kt + 2) * 32);
            }
            compute(kt % 3);
        }
    } else {
        stage_tile(0, 0);
        if (NK > 1) stage_tile(1, 1);
        int cb_ = 0, sb_ = 2;
        #pragma unroll 1
        for (int kt = 0; kt < NK; ++kt) {
            if (kt == NK - 1) asm volatile("s_waitcnt vmcnt(0)");
            else              asm volatile("s_waitcnt vmcnt(3)");
            __builtin_amdgcn_sched_barrier(0);
            __builtin_amdgcn_s_barrier();
            __builtin_amdgcn_sched_barrier(0);
            if (kt + 2 < NK) stage_tile(sb_, kt + 2);
            compute(cb_);
            cb_ = (cb_ == 2) ? 0 : cb_ + 1;
            sb_ = (sb_ == 2) ? 0 : sb_ + 1;
        }
    }

    #pragma unroll
    for (int nf = 0; nf < 4; ++nf) {
        const int col = col0 + wcol * 64 + nf * 16 + (lane & 15);
        const float bv = bias[col];
        #pragma unroll
        for (int mf = 0; mf < 4; ++mf) {
            const int rbase = row0 + wrow * 64 + mf * 16 + (lane >> 4) * 4;
            #pragma unroll
            for (int r = 0; r < 4; ++r) {
                float o = acc[mf][nf][r] + bv;
                if (RELU) o = fmaxf(o, 0.f);
                if constexpr (OUTF32)
                    ((float*)C_)[(size_t)(rbase + r) * N + col] = o;
                else
                    ((u16*)C_)[(size_t)(rbase + r) * N + col] = f2bf(o);
            }
        }
    }
}

// ===========================================================================
// prep: all 7 weight convert+transposes + hist zero in ONE kernel.
// ===========================================================================
__global__ __launch_bounds__(256)
void prep(const float* __restrict__ eW0, const float* __restrict__ eW1,
          const float* __restrict__ eW2, const float* __restrict__ dW0,
          const float* __restrict__ dW1, const float* __restrict__ dW2,
          const float* __restrict__ dW3,
          u16* __restrict__ tE0, u16* __restrict__ tE1, u16* __restrict__ tE2,
          u16* __restrict__ tD0, u16* __restrict__ tD1, u16* __restrict__ tD2,
          u16* __restrict__ tD3, u32* __restrict__ ghist)
{
    const int i = blockIdx.x * 256 + threadIdx.x;
    if (i < 393216) {
        const int k = i >> 9, n = i & 511;
        tE0[(size_t)n * 768 + k] = f2bf(eW0[i]);
    } else if (i < 524288) {
        const int j = i - 393216, k = j >> 8, n = j & 255;
        tE1[(size_t)n * 512 + k] = f2bf(eW1[j]);
    } else if (i < 557056) {
        const int j = i - 524288, k = j >> 7, n = j & 127;
        tE2[(size_t)n * 256 + k] = f2bf(eW2[j]);
    } else if (i < 561152) {
        const int j = i - 557056, k = j >> 7, n = j & 127;
        tD0[(size_t)n * 32 + k] = f2bf(dW0[j]);
    } else if (i < 593920) {
        const int j = i - 561152, k = j >> 8, n = j & 255;
        tD1[(size_t)n * 128 + k] = f2bf(dW1[j]);
    } else if (i < 724992) {
        const int j = i - 593920, k = j >> 9, n = j & 511;
        tD2[(size_t)n * 256 + k] = f2bf(dW2[j]);
    } else if (i < 1118208) {
        const int j = i - 724992, k = j / 768, n = j - k * 768;
        tD3[(size_t)n * 512 + k] = f2bf(dW3[j]);
    } else if (i < 1118976) {
        ghist[i - 1118208] = 0;
    }
}

// ===========================================================================
// VQ kernel, one row per LANE (256 rows/block). Codebook broadcast from LDS.
// Score s = r.c - 0.5||c||^2, argmax strict-> == reference argmin.
// ===========================================================================
__global__ __launch_bounds__(256)
void vq_kernel(const u16* __restrict__ h3, const float* __restrict__ eW3,
               const float* __restrict__ eb3, const float* __restrict__ cb,
               float* __restrict__ r_out, float* __restrict__ e_out,
               float* __restrict__ q_out, u16* __restrict__ se_ws,
               u32* __restrict__ ghist, size_t grow_base)
{
    __shared__ float W3[128 * 32];
    __shared__ float ebv[32];
    __shared__ float clds[256 * 36];
    __shared__ float cc2[256];
    __shared__ u32   lh[NLEV * KCODE];

    const int tid = threadIdx.x;
    const size_t lrow = (size_t)blockIdx.x * 256 + tid;
    const size_t grow = grow_base + lrow;

    for (int i = tid; i < 128 * 32; i += 256) W3[i] = eW3[i];
    if (tid < 32) ebv[tid] = eb3[tid];
    for (int i = tid; i < NLEV * KCODE; i += 256) lh[i] = 0;
    __syncthreads();

    float r[32];
    #pragma unroll
    for (int j = 0; j < 32; ++j) r[j] = ebv[j];
    {
        const u32* hrow = (const u32*)h3 + lrow * 64;
        #pragma unroll 2
        for (int k2 = 0; k2 < 64; ++k2) {
            const u32 v = hrow[k2];
            const float x0 = bf2f(v & 0xffffu), x1 = bf2f(v >> 16);
            const float* w0 = &W3[(2 * k2) * 32];
            const float* w1 = &W3[(2 * k2 + 1) * 32];
            #pragma unroll
            for (int j4 = 0; j4 < 8; ++j4) {
                const float4 a = *(const float4*)&w0[4 * j4];
                const float4 b = *(const float4*)&w1[4 * j4];
                r[4*j4+0] = fmaf(x1, b.x, fmaf(x0, a.x, r[4*j4+0]));
                r[4*j4+1] = fmaf(x1, b.y, fmaf(x0, a.y, r[4*j4+1]));
                r[4*j4+2] = fmaf(x1, b.z, fmaf(x0, a.z, r[4*j4+2]));
                r[4*j4+3] = fmaf(x1, b.w, fmaf(x0, a.w, r[4*j4+3]));
            }
        }
    }

    float z0[32];
    #pragma unroll
    for (int j = 0; j < 32; ++j) z0[j] = r[j];

    #pragma unroll 1
    for (int l = 0; l < NLEV; ++l) {
        __syncthreads();
        {
            const float* cl = cb + ((size_t)l * KCODE + tid) * 32;
            float s = 0.f;
            #pragma unroll
            for (int m = 0; m < 8; ++m) {
                const float4 v = *(const float4*)&cl[4 * m];
                *(float4*)&clds[tid * 36 + 4 * m] = v;
                s = fmaf(v.x, v.x, s); s = fmaf(v.y, v.y, s);
                s = fmaf(v.z, v.z, s); s = fmaf(v.w, v.w, s);
            }
            cc2[tid] = -0.5f * s;
        }
        __syncthreads();

        float best = -FLT_MAX;
        int   bidx = 0;
        #pragma unroll 1
        for (int k = 0; k < KCODE; ++k) {
            const float* ck = &clds[k * 36];
            float d0 = 0.f, d1 = 0.f, d2 = 0.f, d3 = 0.f;
            #pragma unroll
            for (int m = 0; m < 8; m += 4) {
                const float4 v0 = *(const float4*)&ck[4 * (m + 0)];
                const float4 v1 = *(const float4*)&ck[4 * (m + 1)];
                const float4 v2 = *(const float4*)&ck[4 * (m + 2)];
                const float4 v3 = *(const float4*)&ck[4 * (m + 3)];
                d0 = fmaf(r[4*m+0],  v0.x, d0); d0 = fmaf(r[4*m+1],  v0.y, d0);
                d0 = fmaf(r[4*m+2],  v0.z, d0); d0 = fmaf(r[4*m+3],  v0.w, d0);
                d1 = fmaf(r[4*m+4],  v1.x, d1); d1 = fmaf(r[4*m+5],  v1.y, d1);
                d1 = fmaf(r[4*m+6],  v1.z, d1); d1 = fmaf(r[4*m+7],  v1.w, d1);
                d2 = fmaf(r[4*m+8],  v2.x, d2); d2 = fmaf(r[4*m+9],  v2.y, d2);
                d2 = fmaf(r[4*m+10], v2.z, d2); d2 = fmaf(r[4*m+11], v2.w, d2);
                d3 = fmaf(r[4*m+12], v3.x, d3); d3 = fmaf(r[4*m+13], v3.y, d3);
                d3 = fmaf(r[4*m+14], v3.z, d3); d3 = fmaf(r[4*m+15], v3.w, d3);
            }
            const float s = ((d0 + d1) + (d2 + d3)) + cc2[k];
            if (s > best) { best = s; bidx = k; }
        }

        const size_t base = (grow * NLEV + l) * 32;
        const float* ce = &clds[bidx * 36];
        #pragma unroll
        for (int m = 0; m < 8; ++m) {
            const float4 ev = *(const float4*)&ce[4 * m];
            *(float4*)&r_out[base + 4 * m] =
                make_float4(r[4*m+0], r[4*m+1], r[4*m+2], r[4*m+3]);
            *(float4*)&e_out[base + 4 * m] = ev;
            r[4*m+0] -= ev.x; r[4*m+1] -= ev.y;
            r[4*m+2] -= ev.z; r[4*m+3] -= ev.w;
        }
        q_out[grow * NLEV + l] = (float)bidx;
        atomicAdd(&lh[l * KCODE + bidx], 1u);
    }

    u32* sed = (u32*)se_ws + lrow * 16;
    #pragma unroll
    for (int m = 0; m < 16; ++m)
        sed[m] = pack2(z0[2*m] - r[2*m], z0[2*m+1] - r[2*m+1]);

    __syncthreads();
    for (int i = tid; i < NLEV * KCODE; i += 256)
        if (lh[i]) atomicAdd(&ghist[i], lh[i]);
}

__global__ void counts_fin(const u32* __restrict__ g, float* __restrict__ o) {
    if (threadIdx.x < NLEV * KCODE) o[threadIdx.x] = (float)g[threadIdx.x];
}

__global__ __launch_bounds__(256)
void counts_k(const float* __restrict__ q, float* __restrict__ cnt)
{
    const int l = blockIdx.x >> 8;
    const int k = blockIdx.x & 255;
    const float pat = (float)k;
    int c = 0;
    for (int i = threadIdx.x; i < B_TOTAL; i += 256)
        c += (q[(size_t)i * NLEV + l] == pat) ? 1 : 0;
    __shared__ int red[256];
    red[threadIdx.x] = c;
    __syncthreads();
    for (int s = 128; s > 0; s >>= 1) {
        if (threadIdx.x < s) red[threadIdx.x] += red[threadIdx.x + s];
        __syncthreads();
    }
    if (threadIdx.x == 0)
        cnt[blockIdx.x] = (float)red[0];
}

// ===========================================================================
// Fallback path (R6-proven, f32 VALU, zero workspace).
// ===========================================================================
template<int K, int N, bool RELU, bool AGLOBAL>
static __device__ __forceinline__
void layer16(const float* __restrict__ A, size_t grow0,
             const float* __restrict__ W, const float* __restrict__ bias,
             float* __restrict__ C)
{
    constexpr int QPT = N / 128;
    const int tr = threadIdx.x >> 5;
    const int tc = threadIdx.x & 31;
    float acc[2][QPT * 4];
    #pragma unroll
    for (int i = 0; i < 2; ++i)
        #pragma unroll
        for (int j = 0; j < QPT * 4; ++j) acc[i][j] = 0.f;
    #pragma unroll 2
    for (int k0 = 0; k0 < K; k0 += 4) {
        float4 av[2];
        #pragma unroll
        for (int i = 0; i < 2; ++i) {
            if (AGLOBAL)
                av[i] = *(const float4*)&A[(grow0 + tr * 2 + i) * (size_t)K + k0];
            else
                av[i] = *(const float4*)&A[(tr * 2 + i) * K + k0];
        }
        #pragma unroll
        for (int kk = 0; kk < 4; ++kk) {
            #pragma unroll
            for (int q = 0; q < QPT; ++q) {
                const float4 w4 = *(const float4*)&W[(size_t)(k0 + kk) * N + 4 * (tc + 32 * q)];
                #pragma unroll
                for (int i = 0; i < 2; ++i) {
                    const float a = ((const float*)&av[i])[kk];
                    acc[i][4*q+0] = fmaf(a, w4.x, acc[i][4*q+0]);
                    acc[i][4*q+1] = fmaf(a, w4.y, acc[i][4*q+1]);
                    acc[i][4*q+2] = fmaf(a, w4.z, acc[i][4*q+2]);
                    acc[i][4*q+3] = fmaf(a, w4.w, acc[i][4*q+3]);
                }
            }
        }
    }
    #pragma unroll
    for (int q = 0; q < QPT; ++q) {
        const float4 b4 = *(const float4*)&bias[4 * (tc + 32 * q)];
        #pragma unroll
        for (int i = 0; i < 2; ++i) {
            float4 o;
            o.x = acc[i][4*q+0] + b4.x; o.y = acc[i][4*q+1] + b4.y;
            o.z = acc[i][4*q+2] + b4.z; o.w = acc[i][4*q+3] + b4.w;
            if (RELU) {
                o.x = fmaxf(o.x, 0.f); o.y = fmaxf(o.y, 0.f);
                o.z = fmaxf(o.z, 0.f); o.w = fmaxf(o.w, 0.f);
            }
            *(float4*)&C[(tr * 2 + i) * N + 4 * (tc + 32 * q)] = o;
        }
    }
}

static __device__ __forceinline__
void layer_final16(const float* __restrict__ A, const float* __restrict__ W,
                   const float* __restrict__ bias, float* __restrict__ Cg, size_t grow0)
{
    constexpr int QPT = 6;
    const int tr = threadIdx.x >> 5;
    const int tc = threadIdx.x & 31;
    float acc[2][QPT * 4];
    #pragma unroll
    for (int i = 0; i < 2; ++i)
        #pragma unroll
        for (int j = 0; j < QPT * 4; ++j) acc[i][j] = 0.f;
    #pragma unroll 2
    for (int k0 = 0; k0 < 512; k0 += 4) {
        float4 av[2];
        #pragma unroll
        for (int i = 0; i < 2; ++i)
            av[i] = *(const float4*)&A[(tr * 2 + i) * 512 + k0];
        #pragma unroll
        for (int kk = 0; kk < 4; ++kk) {
            #pragma unroll
            for (int q = 0; q < QPT; ++q) {
                const float4 w4 = *(const float4*)&W[(size_t)(k0 + kk) * 768 + 4 * (tc + 32 * q)];
                #pragma unroll
                for (int i = 0; i < 2; ++i) {
                    const float a = ((const float*)&av[i])[kk];
                    acc[i][4*q+0] = fmaf(a, w4.x, acc[i][4*q+0]);
                    acc[i][4*q+1] = fmaf(a, w4.y, acc[i][4*q+1]);
                    acc[i][4*q+2] = fmaf(a, w4.z, acc[i][4*q+2]);
                    acc[i][4*q+3] = fmaf(a, w4.w, acc[i][4*q+3]);
                }
            }
        }
    }
    #pragma unroll
    for (int q = 0; q < QPT; ++q) {
        const float4 b4 = *(const float4*)&bias[4 * (tc + 32 * q)];
        #pragma unroll
        for (int i = 0; i < 2; ++i) {
            float4 s;
            s.x = acc[i][4*q+0] + b4.x; s.y = acc[i][4*q+1] + b4.y;
            s.z = acc[i][4*q+2] + b4.z; s.w = acc[i][4*q+3] + b4.w;
            *(float4*)&Cg[(grow0 + tr * 2 + i) * (size_t)768 + 4 * (tc + 32 * q)] = s;
        }
    }
}

static __device__ __forceinline__
void layer_narrow16(const float* __restrict__ A, const float* __restrict__ W,
                    const float* __restrict__ bias, float* __restrict__ Z)
{
    const int row = threadIdx.x >> 4;
    const int g   = threadIdx.x & 15;
    float a0 = 0.f, a1 = 0.f;
    #pragma unroll 4
    for (int k0 = 0; k0 < 128; k0 += 4) {
        const float4 av = *(const float4*)&A[row * 128 + k0];
        #pragma unroll
        for (int kk = 0; kk < 4; ++kk) {
            const float2 w2 = *(const float2*)&W[(k0 + kk) * 32 + 2 * g];
            const float a = ((const float*)&av)[kk];
            a0 = fmaf(a, w2.x, a0);
            a1 = fmaf(a, w2.y, a1);
        }
    }
    Z[row * 36 + 2 * g + 0] = a0 + bias[2 * g + 0];
    Z[row * 36 + 2 * g + 1] = a1 + bias[2 * g + 1];
}

__global__ __launch_bounds__(256)
void enc_vq_kernel(const float* __restrict__ x,
                   const float* __restrict__ eW0, const float* __restrict__ eb0,
                   const float* __restrict__ eW1, const float* __restrict__ eb1,
                   const float* __restrict__ eW2, const float* __restrict__ eb2,
                   const float* __restrict__ eW3, const float* __restrict__ eb3,
                   const float* __restrict__ cb,
                   float* __restrict__ r_out, float* __restrict__ e_out,
                   float* __restrict__ q_out)
{
    __shared__ __align__(16) char smem[59648];
    float* h1   = (float*)(smem);
    float* h2   = (float*)(smem + 32768);
    float* h3   = (float*)(smem + 49152);
    float* z    = (float*)(smem + 57344);
    float* clds = (float*)(smem);
    float* cc   = (float*)(smem + 36864);

    const size_t grow0 = (size_t)blockIdx.x * 16;
    layer16<768, 512, true, true >(x,  grow0, eW0, eb0, h1);
    __syncthreads();
    layer16<512, 256, true, false>(h1, 0,     eW1, eb1, h2);
    __syncthreads();
    layer16<256, 128, true, false>(h2, 0,     eW2, eb2, h3);
    __syncthreads();
    layer_narrow16(h3, eW3, eb3, z);

    const int row = threadIdx.x >> 4;
    const int g   = threadIdx.x & 15;
    const size_t grow = grow0 + row;

    #pragma unroll 1
    for (int l = 0; l < NLEV; ++l) {
        __syncthreads();
        {
            const float* cl = cb + (size_t)l * KCODE * 32;
            const int t = threadIdx.x;
            float s = 0.f;
            #pragma unroll
            for (int m = 0; m < 8; ++m) {
                const float4 v = *(const float4*)&cl[t * 32 + 4 * m];
                *(float4*)&clds[t * 36 + 4 * m] = v;
                s = fmaf(v.x, v.x, s); s = fmaf(v.y, v.y, s);
                s = fmaf(v.z, v.z, s); s = fmaf(v.w, v.w, s);
            }
            cc[t] = s;
        }
        __syncthreads();

        float r[32];
        #pragma unroll
        for (int m = 0; m < 8; ++m) {
            const float4 v = *(const float4*)&z[row * 36 + 4 * m];
            r[4*m+0] = v.x; r[4*m+1] = v.y; r[4*m+2] = v.z; r[4*m+3] = v.w;
        }
        float rr = 0.f;
        #pragma unroll
        for (int j = 0; j < 32; ++j) rr = fmaf(r[j], r[j], rr);

        float best = FLT_MAX;
        int   bidx = 0x7fffffff;
        #pragma unroll 1
        for (int t = 0; t < 16; ++t) {
            const int k = g + 16 * t;
            const float* ck = &clds[k * 36];
            float d0 = 0.f, d1 = 0.f, d2 = 0.f, d3 = 0.f;
            #pragma unroll
            for (int m = 0; m < 8; m += 4) {
                const float4 v0 = *(const float4*)&ck[4 * (m + 0)];
                const float4 v1 = *(const float4*)&ck[4 * (m + 1)];
                const float4 v2 = *(const float4*)&ck[4 * (m + 2)];
                const float4 v3 = *(const float4*)&ck[4 * (m + 3)];
                d0 = fmaf(r[4*m+0],  v0.x, d0); d0 = fmaf(r[4*m+1],  v0.y, d0);
                d0 = fmaf(r[4*m+2],  v0.z, d0); d0 = fmaf(r[4*m+3],  v0.w, d0);
                d1 = fmaf(r[4*m+4],  v1.x, d1); d1 = fmaf(r[4*m+5],  v1.y, d1);
                d1 = fmaf(r[4*m+6],  v1.z, d1); d1 = fmaf(r[4*m+7],  v1.w, d1);
                d2 = fmaf(r[4*m+8],  v2.x, d2); d2 = fmaf(r[4*m+9],  v2.y, d2);
                d2 = fmaf(r[4*m+10], v2.z, d2); d2 = fmaf(r[4*m+11], v2.w, d2);
                d3 = fmaf(r[4*m+12], v3.x, d3); d3 = fmaf(r[4*m+13], v3.y, d3);
                d3 = fmaf(r[4*m+14], v3.z, d3); d3 = fmaf(r[4*m+15], v3.w, d3);
            }
            const float dot = (d0 + d1) + (d2 + d3);
            const float d = (rr - 2.f * dot) + cc[k];
            if (d < best || (d == best && k < bidx)) { best = d; bidx = k; }
        }
        #pragma unroll
        for (int off = 1; off < 16; off <<= 1) {
            const float ob = __shfl_xor(best, off);
            const int   oi = __shfl_xor(bidx, off);
            if (ob < best || (ob == best && oi < bidx)) { best = ob; bidx = oi; }
        }

        const float evx = clds[bidx * 36 + 2 * g + 0];
        const float evy = clds[bidx * 36 + 2 * g + 1];
        *(float2*)&r_out[(grow * NLEV + l) * 32 + 2 * g] = make_float2(r[2*g], r[2*g+1]);
        *(float2*)&e_out[(grow * NLEV + l) * 32 + 2 * g] = make_float2(evx, evy);
        if (g == 0) q_out[grow * NLEV + l] = (float)bidx;
        z[row * 36 + 2 * g + 0] = r[2 * g + 0] - evx;
        z[row * 36 + 2 * g + 1] = r[2 * g + 1] - evy;
    }
}

__global__ __launch_bounds__(256)
void dec_kernel(const float* __restrict__ e_in,
                const float* __restrict__ dW0, const float* __restrict__ db0,
                const float* __restrict__ dW1, const float* __restrict__ db1,
                const float* __restrict__ dW2, const float* __restrict__ db2,
                const float* __restrict__ dW3, const float* __restrict__ db3,
                float* __restrict__ dec_out)
{
    __shared__ __align__(16) char smem[59392];
    float* h3 = (float*)(smem);
    float* h2 = (float*)(smem + 32768);
    float* h1 = (float*)(smem + 49152);
    float* se = (float*)(smem + 57344);

    const size_t grow0 = (size_t)blockIdx.x * 16;
    const int row = threadIdx.x >> 4;
    const int g   = threadIdx.x & 15;
    {
        const size_t base = ((grow0 + row) * NLEV) * 32 + 2 * g;
        float s0 = 0.f, s1 = 0.f;
        #pragma unroll
        for (int l = 0; l < NLEV; ++l) {
            const float2 v = *(const float2*)&e_in[base + l * 32];
            s0 += v.x; s1 += v.y;
        }
        se[row * 32 + 2 * g + 0] = s0;
        se[row * 32 + 2 * g + 1] = s1;
    }
    __syncthreads();
    layer16<32,  128, true, false>(se, 0, dW0, db0, h1);
    __syncthreads();
    layer16<128, 256, true, false>(h1, 0, dW1, db1, h2);
    __syncthreads();
    layer16<256, 512, true, false>(h2, 0, dW2, db2, h3);
    __syncthreads();
    layer_final16(h3, dW3, db3, dec_out, grow0);
}

// ===========================================================================
extern "C" void kernel_launch(void* const* d_in, const int* in_sizes, int n_in,
                              void* d_out, int out_size, void* d_ws, size_t ws_size,
                              hipStream_t stream)
{
    (void)in_sizes; (void)n_in; (void)out_size;
    const float* x  = (const float*)d_in[0];
    const float* cb = (const float*)d_in[17];
    const float *eW[4], *eb[4], *dW[4], *db[4];
    for (int i = 0; i < 4; ++i) {
        eW[i] = (const float*)d_in[1 + 4 * i];
        eb[i] = (const float*)d_in[2 + 4 * i];
        dW[i] = (const float*)d_in[3 + 4 * i];
        db[i] = (const float*)d_in[4 + 4 * i];
    }

    float* out = (float*)d_out;
    const size_t OFF_R = (size_t)B_TOTAL * IN_DIM;
    const size_t OFF_E = OFF_R + (size_t)B_TOTAL * NLEV * 32;
    const size_t OFF_C = OFF_E + (size_t)B_TOTAL * NLEV * 32;
    const size_t OFF_Q = OFF_C + (size_t)NLEV * KCODE;

    const size_t WTB = 2236416;                 // weights bf16, bytes
    size_t R = 0;
    for (size_t cand = 131072; cand >= 2048; cand >>= 1)
        if (WTB + cand * 3648 + 4096 <= ws_size) { R = cand; break; }

    if (R && d_ws) {
        u16* Wp   = (u16*)d_ws;
        u16* WtE0 = Wp;
        u16* WtE1 = WtE0 + 393216;
        u16* WtE2 = WtE1 + 131072;
        u16* WtD0 = WtE2 + 32768;
        u16* WtD1 = WtD0 + 4096;
        u16* WtD2 = WtD1 + 32768;
        u16* WtD3 = WtD2 + 131072;
        u16* h1   = WtD3 + 393216;
        u16* h2   = h1 + R * 512;
        u16* h3   = h2 + R * 256;
        u16* se   = h3 + R * 128;
        u16* d1   = se + R * 32;
        u16* d2   = d1 + R * 128;
        u16* d3   = d2 + R * 256;
        u32* ghist = (u32*)(d3 + R * 512);

        prep<<<dim3(4371), 256, 0, stream>>>(
            eW[0], eW[1], eW[2], dW[0], dW[1], dW[2], dW[3],
            WtE0, WtE1, WtE2, WtD0, WtD1, WtD2, WtD3, ghist);

        const int nch = B_TOTAL / (int)R;
        const int MB2 = (int)R / 256;          // 256-row blocks
        for (int c = 0; c < nch; ++c) {
            const size_t rb = (size_t)c * R;
            gemm_mfma<768, 512, true,  true,  false><<<dim3(4 * MB2), 512, 0, stream>>>(
                x + rb * 768, WtE0, eb[0], h1);
            gemm_mfma<512, 256, false, true,  false><<<dim3(2 * MB2), 512, 0, stream>>>(
                h1, WtE1, eb[1], h2);
            gemm_mfma<256, 128, false, true,  false><<<dim3(1 * MB2), 512, 0, stream>>>(
                h2, WtE2, eb[2], h3);
            vq_kernel<<<dim3((int)R / 256), 256, 0, stream>>>(
                h3, eW[3], eb[3], cb,
                out + OFF_R, out + OFF_E, out + OFF_Q, se, ghist, rb);
            gemm_mfma<32,  128, false, true,  false><<<dim3(1 * MB2), 512, 0, stream>>>(
                se, WtD0, db[0], d1);
            gemm_mfma<128, 256, false, true,  false><<<dim3(2 * MB2), 512, 0, stream>>>(
                d1, WtD1, db[1], d2);
            gemm_mfma<256, 512, false, true,  false><<<dim3(4 * MB2), 512, 0, stream>>>(
                d2, WtD2, db[2], d3);
            gemm_mfma<512, 768, false, false, true ><<<dim3(6 * MB2), 512, 0, stream>>>(
                d3, WtD3, db[3], out + rb * 768);
        }
        counts_fin<<<1, 768, 0, stream>>>(ghist, out + OFF_C);
    } else {
        enc_vq_kernel<<<dim3(B_TOTAL / 16), 256, 0, stream>>>(
            x, eW[0], eb[0], eW[1], eb[1], eW[2], eb[2], eW[3], eb[3], cb,
            out + OFF_R, out + OFF_E, out + OFF_Q);
        counts_k<<<dim3(NLEV * KCODE), 256, 0, stream>>>(out + OFF_Q, out + OFF_C);
        dec_kernel<<<dim3(B_TOTAL / 16), 256, 0, stream>>>(
            out + OFF_E, dW[0], db[0], dW[1], db[1], dW[2], db[2], dW[3], db[3], out);
    }
}